// Round 4
// baseline (535.184 us; speedup 1.0000x reference)
//
#include <hip/hip_runtime.h>
#include <cstddef>

#define T_SEQ 11
#define STEPS 80

typedef _Float16 f16;
typedef _Float16 f16x4 __attribute__((ext_vector_type(4)));
typedef _Float16 f16x8 __attribute__((ext_vector_type(8)));
typedef float    f32x4 __attribute__((ext_vector_type(4)));

// Gate prescale folded into weights/biases: sigmoid args x -log2(e), tanh
// (n-path) args x +2*log2(e) -> epilogue uses raw exp2/rcp, no per-gate muls.
#define SRC (-1.44269504f)
#define SNC ( 2.88539008f)

// ---- LDS byte offsets (dynamic shared, 142.5 KB total) ----
// Weight frag slots: enc {0:eWhh0,1:eWhh1,2:eWih1}; dec {0:dWhh0,1:dWhh1,
// 2:dWih1,3:composed dWih0*fcW}. Frag(slot,g,jg,ks) = 1KB: lane*16B holds
// sc*W[g*64+jg*16+col][ks*32+quad*8 .. +7] as f16x8 (same as old wfrag).
#define OFF_WF   0         // 4 slots x 24576 B = 98304
#define OFF_HB   98304     // 4 h-buffers x 4096 f16 = 32768 B
#define OFF_XE   131072    // T_SEQ*64 float2 = 5632 B
#define OFF_BIAS 136704    // 4 cell-types x 4 vecs x 64 f32 = 4096 B
#define OFF_XW   140800    // 2 sets x 6 x 64 f32 = 3072 B
#define OFF_FCF  143872    // 2 frags x 512 f16 = 2048 B
#define SMEM_BYTES 145920

__device__ __forceinline__ f32x4 mfma16(f16x8 a, f16x8 b, f32x4 c) {
    return __builtin_amdgcn_mfma_f32_16x16x32_f16(a, b, c, 0, 0, 0);
}
__device__ __forceinline__ float exp2r(float x) { return __builtin_amdgcn_exp2f(x); }

// Stage a 192x64 f32 matrix into frag layout, gate-prescaled, f16.
__device__ __forceinline__ void stage_mat(f16* __restrict__ sw, int slot,
                                          const float* __restrict__ W, int tid) {
    for (int e = tid; e < 12288; e += 1024) {
        const int row = e >> 6, k = e & 63;
        const int g = row >> 6, j = row & 63;
        const int lane = ((k >> 3) & 3) * 16 + (j & 15);
        const float sc = (g == 2) ? SNC : SRC;
        sw[slot * 12288 + g * 4096 + (j >> 4) * 1024 + (k >> 5) * 512 + lane * 8 + (k & 7)]
            = (f16)(sc * W[e]);
    }
}
// Composed decoder-l0 gi: sc*(Wih0[row][0]*fcW[0][k] + Wih0[row][1]*fcW[1][k])
__device__ __forceinline__ void stage_composed(f16* __restrict__ sw, int slot,
                                               const float* __restrict__ Wih0,
                                               const float* __restrict__ fcW, int tid) {
    for (int e = tid; e < 12288; e += 1024) {
        const int row = e >> 6, k = e & 63;
        const int g = row >> 6, j = row & 63;
        const int lane = ((k >> 3) & 3) * 16 + (j & 15);
        const float sc = (g == 2) ? SNC : SRC;
        const float v = Wih0[row * 2] * fcW[k] + Wih0[row * 2 + 1] * fcW[64 + k];
        sw[slot * 12288 + g * 4096 + (j >> 4) * 1024 + (k >> 5) * 512 + lane * 8 + (k & 7)]
            = (f16)(sc * v);
    }
}

// One GRU cell, weights/biases read from LDS. Each wave: 1 batch chunk (mg),
// 16 j-rows (jg). Math identical to the register-resident version.
template<bool XM, int SH, int SX, int CT>
__device__ __forceinline__ void cellL(
    const f16* __restrict__ sw, const float* __restrict__ sb, const float* __restrict__ sxw,
    const f16* __restrict__ Xs, const f16* __restrict__ Hs, f16* __restrict__ Dst,
    f16x4& ho, int wb, int j4, int rom0, int rom1, int wom, float x0, float x1)
{
    const f16* whb = sw + SH * 12288 + wb;
    const f32x4 bR  = *(const f32x4*)(sb + CT * 256 +       j4);
    const f32x4 bZ  = *(const f32x4*)(sb + CT * 256 +  64 + j4);
    const f32x4 bNi = *(const f32x4*)(sb + CT * 256 + 128 + j4);
    const f32x4 bNh = *(const f32x4*)(sb + CT * 256 + 192 + j4);
    f16x8 hb0 = *(const f16x8*)(Hs + rom0);
    f16x8 hb1 = *(const f16x8*)(Hs + rom1);
    f32x4 aR  = mfma16(*(const f16x8*)(whb),        hb0, bR);
    f32x4 aZ  = mfma16(*(const f16x8*)(whb + 4096), hb0, bZ);
    f32x4 aNh = mfma16(*(const f16x8*)(whb + 8192), hb0, bNh);
    aR  = mfma16(*(const f16x8*)(whb +  512),       hb1, aR);
    aZ  = mfma16(*(const f16x8*)(whb + 4096 + 512), hb1, aZ);
    aNh = mfma16(*(const f16x8*)(whb + 8192 + 512), hb1, aNh);
    f32x4 aNi;
    if constexpr (XM) {
        const f16* wxb = sw + SX * 12288 + wb;
        f16x8 xb0 = *(const f16x8*)(Xs + rom0);
        f16x8 xb1 = *(const f16x8*)(Xs + rom1);
        aR  = mfma16(*(const f16x8*)(wxb),               xb0, aR);
        aR  = mfma16(*(const f16x8*)(wxb +  512),        xb1, aR);
        aZ  = mfma16(*(const f16x8*)(wxb + 4096),        xb0, aZ);
        aZ  = mfma16(*(const f16x8*)(wxb + 4096 + 512),  xb1, aZ);
        aNi = mfma16(*(const f16x8*)(wxb + 8192),        xb0, bNi);
        aNi = mfma16(*(const f16x8*)(wxb + 8192 + 512),  xb1, aNi);
    } else {
        const f32x4 xw0 = *(const f32x4*)(sxw +        j4);
        const f32x4 xw1 = *(const f32x4*)(sxw +  64 + j4);
        const f32x4 xw2 = *(const f32x4*)(sxw + 128 + j4);
        const f32x4 xw3 = *(const f32x4*)(sxw + 192 + j4);
        const f32x4 xw4 = *(const f32x4*)(sxw + 256 + j4);
        const f32x4 xw5 = *(const f32x4*)(sxw + 320 + j4);
        aR  += x0 * xw0 + x1 * xw1;
        aZ  += x0 * xw2 + x1 * xw3;
        aNi  = bNi + x0 * xw4 + x1 * xw5;
    }
    f16x4 o;
    #pragma unroll
    for (int i = 0; i < 4; ++i) {
        const float r = __builtin_amdgcn_rcpf(1.f + exp2r(aR[i]));
        const float z = __builtin_amdgcn_rcpf(1.f + exp2r(aZ[i]));
        const float n = 1.f - 2.f * __builtin_amdgcn_rcpf(1.f + exp2r(aNi[i] + r * aNh[i]));
        const float h = n + z * ((float)ho[i] - n);
        o[i] = (f16)h;
    }
    ho = o;
    *(f16x4*)(Dst + wom) = o;
}

// 1024 threads (16 waves = 4/SIMD), one block per CU (142.5 KB LDS).
// launch_bounds(1024,4) caps VGPR at 64 (=256/4, wave64 law measured r1/r3)
// -- mandatory: a 16-wave block is only schedulable at V<=64.
__global__ __launch_bounds__(1024, 4)
void gru_traj_lds1(
    const float* __restrict__ x,
    const float* __restrict__ eWih0, const float* __restrict__ eWhh0,
    const float* __restrict__ ebih0, const float* __restrict__ ebhh0,
    const float* __restrict__ eWih1, const float* __restrict__ eWhh1,
    const float* __restrict__ ebih1, const float* __restrict__ ebhh1,
    const float* __restrict__ dWih0, const float* __restrict__ dWhh0,
    const float* __restrict__ dbih0, const float* __restrict__ dbhh0,
    const float* __restrict__ dWih1, const float* __restrict__ dWhh1,
    const float* __restrict__ dbih1, const float* __restrict__ dbhh1,
    const float* __restrict__ fcW,  const float* __restrict__ fcb,
    float* __restrict__ out)
{
    extern __shared__ char smem[];
    f16*    sw  = (f16*)(smem + OFF_WF);
    f16*    hbb = (f16*)(smem + OFF_HB);
    float2* sxe = (float2*)(smem + OFF_XE);
    float*  sb  = (float*)(smem + OFF_BIAS);
    float*  sxw = (float*)(smem + OFF_XW);
    f16*    sfc = (f16*)(smem + OFF_FCF);
#define HB(i) (hbb + (i) * 4096)

    const int tid  = threadIdx.x;
    const int lane = tid & 63;
    const int wv   = __builtin_amdgcn_readfirstlane(tid >> 6);
    const int jg   = wv >> 2;          // j-group: output rows jg*16..+15
    const int mg   = wv & 3;           // batch chunk: rows mg*16..+15
    const int quad = lane >> 4;
    const int col  = lane & 15;
    const int r0   = blockIdx.x * 64;

    // ---------------- stage encoder weights/biases/x ----------------
    stage_mat(sw, 0, eWhh0, tid);
    stage_mat(sw, 1, eWhh1, tid);
    stage_mat(sw, 2, eWih1, tid);
    {
        const float2* x2 = (const float2*)x;
        for (int i = tid; i < 64 * T_SEQ; i += 1024) {
            const int row = i / T_SEQ, t = i - row * T_SEQ;
            sxe[t * 64 + row] = x2[(size_t)r0 * T_SEQ + i];
        }
    }
    for (int i = tid; i < 4096; i += 1024) { hbb[i] = (f16)0.f; hbb[8192 + i] = (f16)0.f; }
    if (tid < 64) {
        const int j = tid;
        sb[       j] = SRC * (ebih0[j] + ebhh0[j]);
        sb[ 64 + j] = SRC * (ebih0[64 + j] + ebhh0[64 + j]);
        sb[128 + j] = SNC * ebih0[128 + j];
        sb[192 + j] = SNC * ebhh0[128 + j];
        sb[256 +       j] = SRC * (ebih1[j] + ebhh1[j]);
        sb[256 +  64 + j] = SRC * (ebih1[64 + j] + ebhh1[64 + j]);
        sb[256 + 128 + j] = SNC * ebih1[128 + j];
        sb[256 + 192 + j] = SNC * ebhh1[128 + j];
        sxw[      j] = SRC * eWih0[j * 2];
        sxw[ 64 + j] = SRC * eWih0[j * 2 + 1];
        sxw[128 + j] = SRC * eWih0[(64 + j) * 2];
        sxw[192 + j] = SRC * eWih0[(64 + j) * 2 + 1];
        sxw[256 + j] = SNC * eWih0[(128 + j) * 2];
        sxw[320 + j] = SNC * eWih0[(128 + j) * 2 + 1];
    }
    {   // fc frag: lane holds fcW[col][k-slice] for col<2 else 0
        const int e = tid;
        const int ks = e >> 9, rr = e & 511;
        const int lne = rr >> 3, ki = rr & 7;
        const int c = lne & 15, q = lne >> 4;
        const int k = ks * 32 + q * 8 + ki;
        sfc[ks * 512 + lne * 8 + ki] = (c < 2) ? (f16)fcW[c * 64 + k] : (f16)0.f;
    }
    __syncthreads();

    // Per-wave constants (identical swizzle to the passing kernel, w->jg, mt->mg)
    const int c7   = col & 7;
    const int rom0 = col * 64 + ((quad ^ c7) << 3) + mg * 1024;
    const int rom1 = col * 64 + (((4 + quad) ^ c7) << 3) + mg * 1024;
    const int wom  = col * 64 + ((((jg << 1) | (quad >> 1)) ^ c7) << 3) + ((quad & 1) << 2) + mg * 1024;
    const int j4   = jg * 16 + quad * 4;
    const int wb   = lane * 8 + jg * 1024;

    f16x4 ho0, ho1;
    #pragma unroll
    for (int i = 0; i < 4; ++i) { ho0[i] = (f16)0.f; ho1[i] = (f16)0.f; }

    // ---------------- encoder: 11 steps, 1 barrier per cell-pair point ----------
    #pragma unroll 1
    for (int t = 0; t < T_SEQ - 1; t += 2) {
        float2 xv = sxe[t * 64 + mg * 16 + col];
        cellL<false, 0, 0, 0>(sw, sb, sxw, HB(0), HB(0), HB(1), ho0, wb, j4, rom0, rom1, wom, xv.x, xv.y);
        __syncthreads();
        cellL<true, 1, 2, 1>(sw, sb, sxw, HB(1), HB(2), HB(3), ho1, wb, j4, rom0, rom1, wom, 0.f, 0.f);
        xv = sxe[(t + 1) * 64 + mg * 16 + col];
        cellL<false, 0, 0, 0>(sw, sb, sxw, HB(1), HB(1), HB(0), ho0, wb, j4, rom0, rom1, wom, xv.x, xv.y);
        __syncthreads();
        cellL<true, 1, 2, 1>(sw, sb, sxw, HB(0), HB(3), HB(2), ho1, wb, j4, rom0, rom1, wom, 0.f, 0.f);
    }
    {   // t = 10 (even body)
        const float2 xv = sxe[10 * 64 + mg * 16 + col];
        cellL<false, 0, 0, 0>(sw, sb, sxw, HB(0), HB(0), HB(1), ho0, wb, j4, rom0, rom1, wom, xv.x, xv.y);
        __syncthreads();
        cellL<true, 1, 2, 1>(sw, sb, sxw, HB(1), HB(2), HB(3), ho1, wb, j4, rom0, rom1, wom, 0.f, 0.f);
    }
    // now: h0 cur = HB(1), h1 cur = HB(3)

    // ---------------- phase switch: restage decoder weights ----------------
    __syncthreads();   // all waves done reading encoder weight slots
    stage_mat(sw, 0, dWhh0, tid);
    stage_mat(sw, 1, dWhh1, tid);
    stage_mat(sw, 2, dWih1, tid);
    stage_composed(sw, 3, dWih0, fcW, tid);
    if (tid < 64) {
        const int j = tid;
        const float f0 = fcb[0], f1 = fcb[1];
        // D0 biases with fc_b folded through dWih0 (bit-compatible with passing kernel)
        sb[512 +       j] = SRC * (dbih0[j] + dbhh0[j] + dWih0[j * 2] * f0 + dWih0[j * 2 + 1] * f1);
        sb[512 +  64 + j] = SRC * (dbih0[64 + j] + dbhh0[64 + j] + dWih0[(64 + j) * 2] * f0 + dWih0[(64 + j) * 2 + 1] * f1);
        sb[512 + 128 + j] = SNC * (dbih0[128 + j] + dWih0[(128 + j) * 2] * f0 + dWih0[(128 + j) * 2 + 1] * f1);
        sb[512 + 192 + j] = SNC * dbhh0[128 + j];
        sb[768 +       j] = SRC * (dbih1[j] + dbhh1[j]);
        sb[768 +  64 + j] = SRC * (dbih1[64 + j] + dbhh1[64 + j]);
        sb[768 + 128 + j] = SNC * dbih1[128 + j];
        sb[768 + 192 + j] = SNC * dbhh1[128 + j];
        sxw[384 +       j] = SRC * dWih0[j * 2];
        sxw[384 +  64 + j] = SRC * dWih0[j * 2 + 1];
        sxw[384 + 128 + j] = SRC * dWih0[(64 + j) * 2];
        sxw[384 + 192 + j] = SRC * dWih0[(64 + j) * 2 + 1];
        sxw[384 + 256 + j] = SNC * dWih0[(128 + j) * 2];
        sxw[384 + 320 + j] = SNC * dWih0[(128 + j) * 2 + 1];
    }
    __syncthreads();

    f32x4 pb;
    {
        const float f0 = fcb[0], f1 = fcb[1];
        #pragma unroll
        for (int rg = 0; rg < 4; ++rg) pb[rg] = 0.f;
        if (quad == 0) { pb[0] = f0; pb[1] = f1; }
    }
    float* op = out + (size_t)(r0 + mg * 16 + col) * (STEPS * 2);

    // FC: waves jg==0 (one per SIMD) handle the 4 batch chunks.
    auto FCout = [&](const f16* h1c) {
        if (jg == 0) {
            f16x8 a0 = *(const f16x8*)(h1c + rom0);
            f16x8 a1 = *(const f16x8*)(h1c + rom1);
            f32x4 p = mfma16(*(const f16x8*)(sfc + lane * 8), a0, pb);
            p = mfma16(*(const f16x8*)(sfc + 512 + lane * 8), a1, p);
            if (quad == 0) *(float2*)op = make_float2(p[0], p[1]);
        }
        op += 2;
    };

    // ---------------- decoder step 0 (peeled, x-path) ----------------
    {
        const float2 xv0 = sxe[10 * 64 + mg * 16 + col];
        cellL<false, 0, 0, 2>(sw, sb, sxw + 384, HB(1), HB(1), HB(0), ho0, wb, j4, rom0, rom1, wom, xv0.x, xv0.y);
        __syncthreads();
        cellL<true, 1, 2, 3>(sw, sb, sxw, HB(0), HB(3), HB(2), ho1, wb, j4, rom0, rom1, wom, 0.f, 0.f);
        __syncthreads();
        FCout(HB(2));
    }

    // ---------------- decoder: 39 pairs + 1 odd ----------------
    #pragma unroll 1
    for (int sp = 0; sp < 39; ++sp) {
        cellL<true, 0, 3, 2>(sw, sb, sxw, HB(2), HB(0), HB(1), ho0, wb, j4, rom0, rom1, wom, 0.f, 0.f);
        __syncthreads();
        cellL<true, 1, 2, 3>(sw, sb, sxw, HB(1), HB(2), HB(3), ho1, wb, j4, rom0, rom1, wom, 0.f, 0.f);
        __syncthreads();
        FCout(HB(3));
        cellL<true, 0, 3, 2>(sw, sb, sxw, HB(3), HB(1), HB(0), ho0, wb, j4, rom0, rom1, wom, 0.f, 0.f);
        __syncthreads();
        cellL<true, 1, 2, 3>(sw, sb, sxw, HB(0), HB(3), HB(2), ho1, wb, j4, rom0, rom1, wom, 0.f, 0.f);
        __syncthreads();
        FCout(HB(2));
    }
    {   // s = 79 (odd body)
        cellL<true, 0, 3, 2>(sw, sb, sxw, HB(2), HB(0), HB(1), ho0, wb, j4, rom0, rom1, wom, 0.f, 0.f);
        __syncthreads();
        cellL<true, 1, 2, 3>(sw, sb, sxw, HB(1), HB(2), HB(3), ho1, wb, j4, rom0, rom1, wom, 0.f, 0.f);
        __syncthreads();
        FCout(HB(3));
    }
#undef HB
}

extern "C" void kernel_launch(void* const* d_in, const int* in_sizes, int n_in,
                              void* d_out, int out_size, void* d_ws, size_t ws_size,
                              hipStream_t stream) {
    (void)n_in; (void)out_size; (void)d_ws; (void)ws_size;

    const float* x     = (const float*)d_in[0];
    const float* eWih0 = (const float*)d_in[1];
    const float* eWhh0 = (const float*)d_in[2];
    const float* ebih0 = (const float*)d_in[3];
    const float* ebhh0 = (const float*)d_in[4];
    const float* eWih1 = (const float*)d_in[5];
    const float* eWhh1 = (const float*)d_in[6];
    const float* ebih1 = (const float*)d_in[7];
    const float* ebhh1 = (const float*)d_in[8];
    const float* dWih0 = (const float*)d_in[9];
    const float* dWhh0 = (const float*)d_in[10];
    const float* dbih0 = (const float*)d_in[11];
    const float* dbhh0 = (const float*)d_in[12];
    const float* dWih1 = (const float*)d_in[13];
    const float* dWhh1 = (const float*)d_in[14];
    const float* dbih1 = (const float*)d_in[15];
    const float* dbhh1 = (const float*)d_in[16];
    const float* fcW   = (const float*)d_in[17];
    const float* fcb   = (const float*)d_in[18];
    float* out = (float*)d_out;

    static bool attr_done = false;
    if (!attr_done) {
        (void)hipFuncSetAttribute((const void*)gru_traj_lds1,
                                  hipFuncAttributeMaxDynamicSharedMemorySize, SMEM_BYTES);
        attr_done = true;
    }

    const int b = in_sizes[0] / (T_SEQ * 2);   // 32768
    dim3 grid(b / 64), block(1024);
    hipLaunchKernelGGL(gru_traj_lds1, grid, block, SMEM_BYTES, stream,
        x, eWih0, eWhh0, ebih0, ebhh0, eWih1, eWhh1, ebih1, ebhh1,
        dWih0, dWhh0, dbih0, dbhh0, dWih1, dWhh1, dbih1, dbhh1,
        fcW, fcb, out);
}

// Round 5
// 534.519 us; speedup vs baseline: 1.0012x; 1.0012x over previous
//
#include <hip/hip_runtime.h>
#include <cstddef>

#define T_SEQ 11
#define STEPS 80

typedef _Float16 f16;
typedef _Float16 f16x4 __attribute__((ext_vector_type(4)));
typedef _Float16 f16x8 __attribute__((ext_vector_type(8)));
typedef float    f32x4 __attribute__((ext_vector_type(4)));

// Gate prescale folded into weights/biases: sigmoid args x -log2(e), tanh
// (n-path) args x +2*log2(e) -> epilogue uses raw exp2/rcp, no per-gate muls.
#define SRC (-1.44269504f)
#define SNC ( 2.88539008f)

// ---- LDS byte offsets (dynamic shared) ----
#define OFF_WF   0         // 4 slots x 24576 B = 98304
#define OFF_HB   98304     // 4 h-buffers x 4096 f16 = 32768 B
#define OFF_XE   131072    // T_SEQ*64 float2 = 5632 B
#define OFF_BIAS 136704    // 4 cell-types x 4 vecs x 64 f32 = 4096 B
#define OFF_XW   140800    // 2 sets x 6 x 64 f32 = 3072 B
#define OFF_FCF  143872    // 2 frags x 512 f16 = 2048 B
#define OFF_CNT  145920    // 4 group-barrier counters (u32)
#define SMEM_BYTES 145936

__device__ __forceinline__ f32x4 mfma16(f16x8 a, f16x8 b, f32x4 c) {
    return __builtin_amdgcn_mfma_f32_16x16x32_f16(a, b, c, 0, 0, 0);
}
__device__ __forceinline__ float exp2r(float x) { return __builtin_amdgcn_exp2f(x); }

// Stage a 192x64 f32 matrix into frag layout, gate-prescaled, f16.
__device__ __forceinline__ void stage_mat(f16* __restrict__ sw, int slot,
                                          const float* __restrict__ W, int tid) {
    for (int e = tid; e < 12288; e += 1024) {
        const int row = e >> 6, k = e & 63;
        const int g = row >> 6, j = row & 63;
        const int lane = ((k >> 3) & 3) * 16 + (j & 15);
        const float sc = (g == 2) ? SNC : SRC;
        sw[slot * 12288 + g * 4096 + (j >> 4) * 1024 + (k >> 5) * 512 + lane * 8 + (k & 7)]
            = (f16)(sc * W[e]);
    }
}
// Composed decoder-l0 gi: sc*(Wih0[row][0]*fcW[0][k] + Wih0[row][1]*fcW[1][k])
__device__ __forceinline__ void stage_composed(f16* __restrict__ sw, int slot,
                                               const float* __restrict__ Wih0,
                                               const float* __restrict__ fcW, int tid) {
    for (int e = tid; e < 12288; e += 1024) {
        const int row = e >> 6, k = e & 63;
        const int g = row >> 6, j = row & 63;
        const int lane = ((k >> 3) & 3) * 16 + (j & 15);
        const float sc = (g == 2) ? SNC : SRC;
        const float v = Wih0[row * 2] * fcW[k] + Wih0[row * 2 + 1] * fcW[64 + k];
        sw[slot * 12288 + g * 4096 + (j >> 4) * 1024 + (k >> 5) * 512 + lane * 8 + (k & 7)]
            = (f16)(sc * v);
    }
}

// One GRU cell, weights/biases read from LDS. Each wave: 1 batch chunk (mg),
// 16 j-rows (jg). Math identical to round-4 (bit-compatible).
template<bool XM, int SH, int SX, int CT>
__device__ __forceinline__ void cellL(
    const f16* __restrict__ sw, const float* __restrict__ sb, const float* __restrict__ sxw,
    const f16* __restrict__ Xs, const f16* __restrict__ Hs, f16* __restrict__ Dst,
    f16x4& ho, int wb, int j4, int rom0, int rom1, int wom, float x0, float x1)
{
    const f16* whb = sw + SH * 12288 + wb;
    const f32x4 bR  = *(const f32x4*)(sb + CT * 256 +       j4);
    const f32x4 bZ  = *(const f32x4*)(sb + CT * 256 +  64 + j4);
    const f32x4 bNi = *(const f32x4*)(sb + CT * 256 + 128 + j4);
    const f32x4 bNh = *(const f32x4*)(sb + CT * 256 + 192 + j4);
    f16x8 hb0 = *(const f16x8*)(Hs + rom0);
    f16x8 hb1 = *(const f16x8*)(Hs + rom1);
    f32x4 aR  = mfma16(*(const f16x8*)(whb),        hb0, bR);
    f32x4 aZ  = mfma16(*(const f16x8*)(whb + 4096), hb0, bZ);
    f32x4 aNh = mfma16(*(const f16x8*)(whb + 8192), hb0, bNh);
    aR  = mfma16(*(const f16x8*)(whb +  512),       hb1, aR);
    aZ  = mfma16(*(const f16x8*)(whb + 4096 + 512), hb1, aZ);
    aNh = mfma16(*(const f16x8*)(whb + 8192 + 512), hb1, aNh);
    f32x4 aNi;
    if constexpr (XM) {
        const f16* wxb = sw + SX * 12288 + wb;
        f16x8 xb0 = *(const f16x8*)(Xs + rom0);
        f16x8 xb1 = *(const f16x8*)(Xs + rom1);
        aR  = mfma16(*(const f16x8*)(wxb),               xb0, aR);
        aR  = mfma16(*(const f16x8*)(wxb +  512),        xb1, aR);
        aZ  = mfma16(*(const f16x8*)(wxb + 4096),        xb0, aZ);
        aZ  = mfma16(*(const f16x8*)(wxb + 4096 + 512),  xb1, aZ);
        aNi = mfma16(*(const f16x8*)(wxb + 8192),        xb0, bNi);
        aNi = mfma16(*(const f16x8*)(wxb + 8192 + 512),  xb1, aNi);
    } else {
        const f32x4 xw0 = *(const f32x4*)(sxw +        j4);
        const f32x4 xw1 = *(const f32x4*)(sxw +  64 + j4);
        const f32x4 xw2 = *(const f32x4*)(sxw + 128 + j4);
        const f32x4 xw3 = *(const f32x4*)(sxw + 192 + j4);
        const f32x4 xw4 = *(const f32x4*)(sxw + 256 + j4);
        const f32x4 xw5 = *(const f32x4*)(sxw + 320 + j4);
        aR  += x0 * xw0 + x1 * xw1;
        aZ  += x0 * xw2 + x1 * xw3;
        aNi  = bNi + x0 * xw4 + x1 * xw5;
    }
    f16x4 o;
    #pragma unroll
    for (int i = 0; i < 4; ++i) {
        const float r = __builtin_amdgcn_rcpf(1.f + exp2r(aR[i]));
        const float z = __builtin_amdgcn_rcpf(1.f + exp2r(aZ[i]));
        const float n = 1.f - 2.f * __builtin_amdgcn_rcpf(1.f + exp2r(aNi[i] + r * aNh[i]));
        const float h = n + z * ((float)ho[i] - n);
        o[i] = (f16)h;
    }
    ho = o;
    *(f16x4*)(Dst + wom) = o;
}

// 1024 threads (16 waves = 4/SIMD), one block per CU. V capped at 64 via
// launch_bounds(1024,4) (register law measured r1/r3: waves/SIMD = 256/V).
// NEW vs round-4: block-wide __syncthreads() in the recurrence replaced by
// per-mg-group barriers (LDS atomic + spin). Cross-wave data dependence is
// mg-group-local (wave (jg,mg) writes h[jg-rows, mg-cols]; consumers read
// h[*, same mg]), and the 4 waves of group mg sit on SIMD mg (round-robin
// placement) -> 4 independent de-phased streams; LDS bursts of one group
// overlap VALU of another (r4 showed them serialized: VALU 57.5%, idle
// ~= LDS burst time).
__global__ __launch_bounds__(1024, 4)
void gru_traj_lds2(
    const float* __restrict__ x,
    const float* __restrict__ eWih0, const float* __restrict__ eWhh0,
    const float* __restrict__ ebih0, const float* __restrict__ ebhh0,
    const float* __restrict__ eWih1, const float* __restrict__ eWhh1,
    const float* __restrict__ ebih1, const float* __restrict__ ebhh1,
    const float* __restrict__ dWih0, const float* __restrict__ dWhh0,
    const float* __restrict__ dbih0, const float* __restrict__ dbhh0,
    const float* __restrict__ dWih1, const float* __restrict__ dWhh1,
    const float* __restrict__ dbih1, const float* __restrict__ dbhh1,
    const float* __restrict__ fcW,  const float* __restrict__ fcb,
    float* __restrict__ out)
{
    extern __shared__ char smem[];
    f16*    sw  = (f16*)(smem + OFF_WF);
    f16*    hbb = (f16*)(smem + OFF_HB);
    float2* sxe = (float2*)(smem + OFF_XE);
    float*  sb  = (float*)(smem + OFF_BIAS);
    float*  sxw = (float*)(smem + OFF_XW);
    f16*    sfc = (f16*)(smem + OFF_FCF);
    unsigned* cnt = (unsigned*)(smem + OFF_CNT);
#define HB(i) (hbb + (i) * 4096)

    const int tid  = threadIdx.x;
    const int lane = tid & 63;
    const int wv   = __builtin_amdgcn_readfirstlane(tid >> 6);
    const int jg   = wv >> 2;          // j-group: output rows jg*16..+15
    const int mg   = wv & 2 ? (wv & 3) : (wv & 3);  // batch chunk
    const int quad = lane >> 4;
    const int col  = lane & 15;
    const int r0   = blockIdx.x * 64;

    // ---- group barrier: 4 waves sharing mg sync among themselves ----
    unsigned tgt = 0;
    auto gbar = [&]() {
        asm volatile("s_waitcnt lgkmcnt(0)" ::: "memory");
        if (lane == 0)
            __hip_atomic_fetch_add(cnt + mg, 1u, __ATOMIC_RELAXED, __HIP_MEMORY_SCOPE_WORKGROUP);
        tgt += 4;
        while (__hip_atomic_load(cnt + mg, __ATOMIC_RELAXED, __HIP_MEMORY_SCOPE_WORKGROUP) < tgt)
            __builtin_amdgcn_s_sleep(1);
        __builtin_amdgcn_sched_barrier(0);
        asm volatile("" ::: "memory");
    };

    // ---------------- stage encoder weights/biases/x ----------------
    if (tid < 4) cnt[tid] = 0u;
    stage_mat(sw, 0, eWhh0, tid);
    stage_mat(sw, 1, eWhh1, tid);
    stage_mat(sw, 2, eWih1, tid);
    {
        const float2* x2 = (const float2*)x;
        for (int i = tid; i < 64 * T_SEQ; i += 1024) {
            const int row = i / T_SEQ, t = i - row * T_SEQ;
            sxe[t * 64 + row] = x2[(size_t)r0 * T_SEQ + i];
        }
    }
    for (int i = tid; i < 4096; i += 1024) { hbb[i] = (f16)0.f; hbb[8192 + i] = (f16)0.f; }
    if (tid < 64) {
        const int j = tid;
        sb[       j] = SRC * (ebih0[j] + ebhh0[j]);
        sb[ 64 + j] = SRC * (ebih0[64 + j] + ebhh0[64 + j]);
        sb[128 + j] = SNC * ebih0[128 + j];
        sb[192 + j] = SNC * ebhh0[128 + j];
        sb[256 +       j] = SRC * (ebih1[j] + ebhh1[j]);
        sb[256 +  64 + j] = SRC * (ebih1[64 + j] + ebhh1[64 + j]);
        sb[256 + 128 + j] = SNC * ebih1[128 + j];
        sb[256 + 192 + j] = SNC * ebhh1[128 + j];
        sxw[      j] = SRC * eWih0[j * 2];
        sxw[ 64 + j] = SRC * eWih0[j * 2 + 1];
        sxw[128 + j] = SRC * eWih0[(64 + j) * 2];
        sxw[192 + j] = SRC * eWih0[(64 + j) * 2 + 1];
        sxw[256 + j] = SNC * eWih0[(128 + j) * 2];
        sxw[320 + j] = SNC * eWih0[(128 + j) * 2 + 1];
    }
    {   // fc frag: lane holds fcW[col][k-slice] for col<2 else 0
        const int e = tid;
        const int ks = e >> 9, rr = e & 511;
        const int lne = rr >> 3, ki = rr & 7;
        const int c = lne & 15, q = lne >> 4;
        const int k = ks * 32 + q * 8 + ki;
        sfc[ks * 512 + lne * 8 + ki] = (c < 2) ? (f16)fcW[c * 64 + k] : (f16)0.f;
    }
    __syncthreads();

    // Per-wave constants (identical to round-4)
    const int c7   = col & 7;
    const int rom0 = col * 64 + ((quad ^ c7) << 3) + mg * 1024;
    const int rom1 = col * 64 + (((4 + quad) ^ c7) << 3) + mg * 1024;
    const int wom  = col * 64 + ((((jg << 1) | (quad >> 1)) ^ c7) << 3) + ((quad & 1) << 2) + mg * 1024;
    const int j4   = jg * 16 + quad * 4;
    const int wb   = lane * 8 + jg * 1024;

    f16x4 ho0, ho1;
    #pragma unroll
    for (int i = 0; i < 4; ++i) { ho0[i] = (f16)0.f; ho1[i] = (f16)0.f; }

    // ---------------- encoder: group barriers only ----------------
    #pragma unroll 1
    for (int t = 0; t < T_SEQ - 1; t += 2) {
        float2 xv = sxe[t * 64 + mg * 16 + col];
        cellL<false, 0, 0, 0>(sw, sb, sxw, HB(0), HB(0), HB(1), ho0, wb, j4, rom0, rom1, wom, xv.x, xv.y);
        gbar();
        cellL<true, 1, 2, 1>(sw, sb, sxw, HB(1), HB(2), HB(3), ho1, wb, j4, rom0, rom1, wom, 0.f, 0.f);
        xv = sxe[(t + 1) * 64 + mg * 16 + col];
        cellL<false, 0, 0, 0>(sw, sb, sxw, HB(1), HB(1), HB(0), ho0, wb, j4, rom0, rom1, wom, xv.x, xv.y);
        gbar();
        cellL<true, 1, 2, 1>(sw, sb, sxw, HB(0), HB(3), HB(2), ho1, wb, j4, rom0, rom1, wom, 0.f, 0.f);
    }
    {   // t = 10 (even body)
        const float2 xv = sxe[10 * 64 + mg * 16 + col];
        cellL<false, 0, 0, 0>(sw, sb, sxw, HB(0), HB(0), HB(1), ho0, wb, j4, rom0, rom1, wom, xv.x, xv.y);
        gbar();
        cellL<true, 1, 2, 1>(sw, sb, sxw, HB(1), HB(2), HB(3), ho1, wb, j4, rom0, rom1, wom, 0.f, 0.f);
    }
    // now: h0 cur = HB(1), h1 cur = HB(3)

    // ---------------- phase switch: restage decoder weights (full sync) ------
    __syncthreads();   // all groups done reading encoder weight slots
    stage_mat(sw, 0, dWhh0, tid);
    stage_mat(sw, 1, dWhh1, tid);
    stage_mat(sw, 2, dWih1, tid);
    stage_composed(sw, 3, dWih0, fcW, tid);
    if (tid < 64) {
        const int j = tid;
        const float f0 = fcb[0], f1 = fcb[1];
        sb[512 +       j] = SRC * (dbih0[j] + dbhh0[j] + dWih0[j * 2] * f0 + dWih0[j * 2 + 1] * f1);
        sb[512 +  64 + j] = SRC * (dbih0[64 + j] + dbhh0[64 + j] + dWih0[(64 + j) * 2] * f0 + dWih0[(64 + j) * 2 + 1] * f1);
        sb[512 + 128 + j] = SNC * (dbih0[128 + j] + dWih0[(128 + j) * 2] * f0 + dWih0[(128 + j) * 2 + 1] * f1);
        sb[512 + 192 + j] = SNC * dbhh0[128 + j];
        sb[768 +       j] = SRC * (dbih1[j] + dbhh1[j]);
        sb[768 +  64 + j] = SRC * (dbih1[64 + j] + dbhh1[64 + j]);
        sb[768 + 128 + j] = SNC * dbih1[128 + j];
        sb[768 + 192 + j] = SNC * dbhh1[128 + j];
        sxw[384 +       j] = SRC * dWih0[j * 2];
        sxw[384 +  64 + j] = SRC * dWih0[j * 2 + 1];
        sxw[384 + 128 + j] = SRC * dWih0[(64 + j) * 2];
        sxw[384 + 192 + j] = SRC * dWih0[(64 + j) * 2 + 1];
        sxw[384 + 256 + j] = SNC * dWih0[(128 + j) * 2];
        sxw[384 + 320 + j] = SNC * dWih0[(128 + j) * 2 + 1];
    }
    __syncthreads();

    f32x4 pb;
    {
        const float f0 = fcb[0], f1 = fcb[1];
        #pragma unroll
        for (int rg = 0; rg < 4; ++rg) pb[rg] = 0.f;
        if (quad == 0) { pb[0] = f0; pb[1] = f1; }
    }
    float* op = out + (size_t)(r0 + mg * 16 + col) * (STEPS * 2);

    // FC: jg==0 wave of each group handles its own mg chunk (group-local).
    auto FCout = [&](const f16* h1c) {
        if (jg == 0) {
            f16x8 a0 = *(const f16x8*)(h1c + rom0);
            f16x8 a1 = *(const f16x8*)(h1c + rom1);
            f32x4 p = mfma16(*(const f16x8*)(sfc + lane * 8), a0, pb);
            p = mfma16(*(const f16x8*)(sfc + 512 + lane * 8), a1, p);
            if (quad == 0) *(float2*)op = make_float2(p[0], p[1]);
        }
        op += 2;
    };

    // ---------------- decoder step 0 (peeled, x-path) ----------------
    {
        const float2 xv0 = sxe[10 * 64 + mg * 16 + col];
        cellL<false, 0, 0, 2>(sw, sb, sxw + 384, HB(1), HB(1), HB(0), ho0, wb, j4, rom0, rom1, wom, xv0.x, xv0.y);
        gbar();
        cellL<true, 1, 2, 3>(sw, sb, sxw, HB(0), HB(3), HB(2), ho1, wb, j4, rom0, rom1, wom, 0.f, 0.f);
        gbar();
        FCout(HB(2));
    }

    // ---------------- decoder: 39 pairs + 1 odd, group barriers ----------
    #pragma unroll 1
    for (int sp = 0; sp < 39; ++sp) {
        cellL<true, 0, 3, 2>(sw, sb, sxw, HB(2), HB(0), HB(1), ho0, wb, j4, rom0, rom1, wom, 0.f, 0.f);
        gbar();
        cellL<true, 1, 2, 3>(sw, sb, sxw, HB(1), HB(2), HB(3), ho1, wb, j4, rom0, rom1, wom, 0.f, 0.f);
        gbar();
        FCout(HB(3));
        cellL<true, 0, 3, 2>(sw, sb, sxw, HB(3), HB(1), HB(0), ho0, wb, j4, rom0, rom1, wom, 0.f, 0.f);
        gbar();
        cellL<true, 1, 2, 3>(sw, sb, sxw, HB(0), HB(3), HB(2), ho1, wb, j4, rom0, rom1, wom, 0.f, 0.f);
        gbar();
        FCout(HB(2));
    }
    {   // s = 79 (odd body)
        cellL<true, 0, 3, 2>(sw, sb, sxw, HB(2), HB(0), HB(1), ho0, wb, j4, rom0, rom1, wom, 0.f, 0.f);
        gbar();
        cellL<true, 1, 2, 3>(sw, sb, sxw, HB(1), HB(2), HB(3), ho1, wb, j4, rom0, rom1, wom, 0.f, 0.f);
        gbar();
        FCout(HB(3));
    }
#undef HB
}

extern "C" void kernel_launch(void* const* d_in, const int* in_sizes, int n_in,
                              void* d_out, int out_size, void* d_ws, size_t ws_size,
                              hipStream_t stream) {
    (void)n_in; (void)out_size; (void)d_ws; (void)ws_size;

    const float* x     = (const float*)d_in[0];
    const float* eWih0 = (const float*)d_in[1];
    const float* eWhh0 = (const float*)d_in[2];
    const float* ebih0 = (const float*)d_in[3];
    const float* ebhh0 = (const float*)d_in[4];
    const float* eWih1 = (const float*)d_in[5];
    const float* eWhh1 = (const float*)d_in[6];
    const float* ebih1 = (const float*)d_in[7];
    const float* ebhh1 = (const float*)d_in[8];
    const float* dWih0 = (const float*)d_in[9];
    const float* dWhh0 = (const float*)d_in[10];
    const float* dbih0 = (const float*)d_in[11];
    const float* dbhh0 = (const float*)d_in[12];
    const float* dWih1 = (const float*)d_in[13];
    const float* dWhh1 = (const float*)d_in[14];
    const float* dbih1 = (const float*)d_in[15];
    const float* dbhh1 = (const float*)d_in[16];
    const float* fcW   = (const float*)d_in[17];
    const float* fcb   = (const float*)d_in[18];
    float* out = (float*)d_out;

    static bool attr_done = false;
    if (!attr_done) {
        (void)hipFuncSetAttribute((const void*)gru_traj_lds2,
                                  hipFuncAttributeMaxDynamicSharedMemorySize, SMEM_BYTES);
        attr_done = true;
    }

    const int b = in_sizes[0] / (T_SEQ * 2);   // 32768
    dim3 grid(b / 64), block(1024);
    hipLaunchKernelGGL(gru_traj_lds2, grid, block, SMEM_BYTES, stream,
        x, eWih0, eWhh0, ebih0, ebhh0, eWih1, eWhh1, ebih1, ebhh1,
        dWih0, dWhh0, dbih0, dbhh0, dWih1, dWhh1, dbih1, dbhh1,
        fcW, fcb, out);
}

// Round 6
// 465.879 us; speedup vs baseline: 1.1488x; 1.1473x over previous
//
#include <hip/hip_runtime.h>
#include <cstddef>

#define T_SEQ 11
#define STEPS 80

typedef _Float16 f16;
typedef _Float16 f16x4 __attribute__((ext_vector_type(4)));
typedef _Float16 f16x8 __attribute__((ext_vector_type(8)));
typedef float    f32x4 __attribute__((ext_vector_type(4)));

// Gate prescale folded into weights/biases: sigmoid args x -log2(e), tanh
// (n-path) args x +2*log2(e) -> epilogue uses raw exp2/rcp, no per-gate muls.
#define SRC (-1.44269504f)
#define SNC ( 2.88539008f)

__device__ __forceinline__ f32x4 mfma16(f16x8 a, f16x8 b, f32x4 c) {
    return __builtin_amdgcn_mfma_f32_16x16x32_f16(a, b, c, 0, 0, 0);
}
__device__ __forceinline__ float exp2r(float x) { return __builtin_amdgcn_exp2f(x); }

// A-frag: lane holds sc*W[row][k0..k0+7].
__device__ __forceinline__ f16x8 wfrag(const float* __restrict__ W, int row, int k0, float sc) {
    f16x8 r;
    #pragma unroll
    for (int i = 0; i < 8; ++i) r[i] = (f16)(sc * W[row * 64 + k0 + i]);
    return r;
}
// Composed decoder-l0 gi weights: sc*(Wih0[g][0]*fcW[0][k] + Wih0[g][1]*fcW[1][k])
__device__ __forceinline__ f16x8 cfrag(const float* __restrict__ Wih0,
                                       const float* __restrict__ fcW, int row, int k0, float sc) {
    f16x8 r;
    #pragma unroll
    for (int i = 0; i < 8; ++i)
        r[i] = (f16)(sc * (Wih0[row * 2] * fcW[k0 + i] + Wih0[row * 2 + 1] * fcW[64 + k0 + i]));
    return r;
}

// Weight fragments ONLY — biases live in LDS now. Held regs: 12 f16x8 = 48
// per set, 96 for both (was 128 with biases). r0-r5 ledger: reported V=128
// -> 2 waves/SIMD (true total ~190 incl. parked accs); cutting held state
// below the quantum is the only path to 3 waves/SIMD with weights resident.
struct WSet {
    f16x8 xR[2], xZ[2], xN[2];   // gi-source weights (MFMA path)
    f16x8 hR[2], hZ[2], hN[2];   // recurrent weights
};

__device__ __forceinline__ void load_h_frags(WSet& W, const float* __restrict__ Whh,
                                             int jA, int quad)
{
    #pragma unroll
    for (int ks = 0; ks < 2; ++ks) {
        const int k0 = ks * 32 + quad * 8;
        W.hR[ks] = wfrag(Whh, jA,       k0, SRC);
        W.hZ[ks] = wfrag(Whh, jA + 64,  k0, SRC);
        W.hN[ks] = wfrag(Whh, jA + 128, k0, SNC);
    }
}
__device__ __forceinline__ void load_x_frags(WSet& W, const float* __restrict__ Wx,
                                             int jA, int quad)
{
    #pragma unroll
    for (int ks = 0; ks < 2; ++ks) {
        const int k0 = ks * 32 + quad * 8;
        W.xR[ks] = wfrag(Wx, jA,       k0, SRC);
        W.xZ[ks] = wfrag(Wx, jA + 64,  k0, SRC);
        W.xN[ks] = wfrag(Wx, jA + 128, k0, SNC);
    }
}

// One GRU cell, D[j][row]. 32 batch rows per block -> 2 mt chunks of 16.
// Biases read from LDS per cell (CT selects cell type slot), transient regs.
template<bool XM, int CT>
__device__ __forceinline__ void cell(const WSet& W, const float* __restrict__ sb,
    const f16* __restrict__ Xs, const f16* __restrict__ Hs, f16* __restrict__ Dst,
    f16x4 (&ho)[2],
    const f32x4* __restrict__ xw, const float2* __restrict__ xv,
    int j4, int ro0, int ro1, int wo)
{
    const f32x4 bR  = *(const f32x4*)(sb + CT * 256 +       j4);
    const f32x4 bZ  = *(const f32x4*)(sb + CT * 256 +  64 + j4);
    const f32x4 bNi = *(const f32x4*)(sb + CT * 256 + 128 + j4);
    const f32x4 bNh = *(const f32x4*)(sb + CT * 256 + 192 + j4);
    #pragma unroll
    for (int mt = 0; mt < 2; ++mt) {
        const int mo = mt * 1024;
        f16x8 hb0 = *(const f16x8*)(Hs + ro0 + mo);
        f16x8 hb1 = *(const f16x8*)(Hs + ro1 + mo);
        f32x4 aR  = mfma16(W.hR[0], hb0, bR);
        f32x4 aZ  = mfma16(W.hZ[0], hb0, bZ);
        f32x4 aNh = mfma16(W.hN[0], hb0, bNh);
        aR  = mfma16(W.hR[1], hb1, aR);
        aZ  = mfma16(W.hZ[1], hb1, aZ);
        aNh = mfma16(W.hN[1], hb1, aNh);
        f32x4 aNi;
        if constexpr (XM) {
            f16x8 xb0 = *(const f16x8*)(Xs + ro0 + mo);
            f16x8 xb1 = *(const f16x8*)(Xs + ro1 + mo);
            aR  = mfma16(W.xR[0], xb0, aR);    aR  = mfma16(W.xR[1], xb1, aR);
            aZ  = mfma16(W.xZ[0], xb0, aZ);    aZ  = mfma16(W.xZ[1], xb1, aZ);
            aNi = mfma16(W.xN[0], xb0, bNi);   aNi = mfma16(W.xN[1], xb1, aNi);
        } else {
            const float x0 = xv[mt].x, x1 = xv[mt].y;
            aR  += x0 * xw[0] + x1 * xw[1];
            aZ  += x0 * xw[2] + x1 * xw[3];
            aNi  = bNi + x0 * xw[4] + x1 * xw[5];
        }
        f16x4 o;
        #pragma unroll
        for (int i = 0; i < 4; ++i) {
            const float r = __builtin_amdgcn_rcpf(1.f + exp2r(aR[i]));
            const float z = __builtin_amdgcn_rcpf(1.f + exp2r(aZ[i]));
            const float n = 1.f - 2.f * __builtin_amdgcn_rcpf(1.f + exp2r(aNi[i] + r * aNh[i]));
            const float h = n + z * ((float)ho[mt][i] - n);
            o[i] = (f16)h;
        }
        ho[mt] = o;
        *(f16x4*)(Dst + wo + mo) = o;
    }
}

// launch_bounds(256,3): cap = 512/3 ~ 170 total regs. Natural usage after
// bias eviction ~150-160 -> fits without the r1 demotion cliff, and the
// allocator targets 3 waves/SIMD instead of 2.
__global__ __launch_bounds__(256, 3)
void gru_traj_mfma11(
    const float* __restrict__ x,
    const float* __restrict__ eWih0, const float* __restrict__ eWhh0,
    const float* __restrict__ ebih0, const float* __restrict__ ebhh0,
    const float* __restrict__ eWih1, const float* __restrict__ eWhh1,
    const float* __restrict__ ebih1, const float* __restrict__ ebhh1,
    const float* __restrict__ dWih0, const float* __restrict__ dWhh0,
    const float* __restrict__ dbih0, const float* __restrict__ dbhh0,
    const float* __restrict__ dWih1, const float* __restrict__ dWhh1,
    const float* __restrict__ dbih1, const float* __restrict__ dbhh1,
    const float* __restrict__ fcW,  const float* __restrict__ fcb,
    float* __restrict__ out)
{
    // buffers: [0,1]=h0 double-buffer, [2,3]=h1 double-buffer, XOR-swizzled.
    __shared__ f16 hbuf[4][32 * 64];     // 16 KB
    __shared__ float2 xe[T_SEQ * 32];    // [t][row], 2.75 KB
    __shared__ float sbias[4 * 256];     // 4 cell types x {bR,bZ,bNi,bNh}[64], 4 KB

    const int tid  = threadIdx.x;
    const int lane = tid & 63;
    const int w    = __builtin_amdgcn_readfirstlane(tid >> 6);
    const int quad = lane >> 4;
    const int col  = lane & 15;
    const int r0   = blockIdx.x * 32;

    // coalesced x staging: consecutive tid -> consecutive global float2
    {
        const float2* x2 = (const float2*)x;
        for (int i = tid; i < 32 * T_SEQ; i += 256) {
            const int row = i / T_SEQ, t = i - row * T_SEQ;
            xe[t * 32 + row] = x2[(size_t)r0 * T_SEQ + i];
        }
    }
    for (int i = tid; i < 32 * 64; i += 256) { hbuf[0][i] = (f16)0.f; hbuf[2][i] = (f16)0.f; }
    if (tid < 64) {   // encoder biases -> LDS (slots 0: enc-l0, 1: enc-l1)
        const int j = tid;
        sbias[       j] = SRC * (ebih0[j] + ebhh0[j]);
        sbias[ 64 + j] = SRC * (ebih0[64 + j] + ebhh0[64 + j]);
        sbias[128 + j] = SNC * ebih0[128 + j];
        sbias[192 + j] = SNC * ebhh0[128 + j];
        sbias[256 +       j] = SRC * (ebih1[j] + ebhh1[j]);
        sbias[256 +  64 + j] = SRC * (ebih1[64 + j] + ebhh1[64 + j]);
        sbias[256 + 128 + j] = SNC * ebih1[128 + j];
        sbias[256 + 192 + j] = SNC * ebhh1[128 + j];
    }

    // Swizzle (halves): phys(row,k) = row*64 + (((k>>3)^(row&7))<<3) + (k&7)
    const int c7  = col & 7;
    const int ro0 = col * 64 + ((quad ^ c7) << 3);
    const int ro1 = col * 64 + (((4 + quad) ^ c7) << 3);
    const int wo  = col * 64 + ((((w << 1) | (quad >> 1)) ^ c7) << 3) + ((quad & 1) << 2);

    const int jA = w * 16 + col;
    const int j4 = w * 16 + quad * 4;

    f16x4 ho0[2], ho1[2];
    #pragma unroll
    for (int mt = 0; mt < 2; ++mt) {
        #pragma unroll
        for (int i = 0; i < 4; ++i) { ho0[mt][i] = (f16)0.f; ho1[mt][i] = (f16)0.f; }
    }

    WSet W0, W1;
    load_h_frags(W0, eWhh0, jA, quad);
    load_h_frags(W1, eWhh1, jA, quad);
    load_x_frags(W1, eWih1, jA, quad);
    {
        f32x4 xw[6];
        #pragma unroll
        for (int rg = 0; rg < 4; ++rg) {
            xw[0][rg] = SRC * eWih0[(j4 + rg) * 2];        xw[1][rg] = SRC * eWih0[(j4 + rg) * 2 + 1];
            xw[2][rg] = SRC * eWih0[(64 + j4 + rg) * 2];   xw[3][rg] = SRC * eWih0[(64 + j4 + rg) * 2 + 1];
            xw[4][rg] = SNC * eWih0[(128 + j4 + rg) * 2];  xw[5][rg] = SNC * eWih0[(128 + j4 + rg) * 2 + 1];
        }
        __syncthreads();

        // ---------------- encoder: static buffers, 1 barrier/step ----------------
        #pragma unroll 1
        for (int t = 0; t < T_SEQ - 1; t += 2) {
            float2 xv[2];
            #pragma unroll
            for (int mt = 0; mt < 2; ++mt) xv[mt] = xe[t * 32 + mt * 16 + col];
            cell<false, 0>(W0, sbias, hbuf[0], hbuf[0], hbuf[1], ho0, xw, xv, j4, ro0, ro1, wo);
            __syncthreads();
            cell<true, 1>(W1, sbias, hbuf[1], hbuf[2], hbuf[3], ho1, nullptr, nullptr, j4, ro0, ro1, wo);
            #pragma unroll
            for (int mt = 0; mt < 2; ++mt) xv[mt] = xe[(t + 1) * 32 + mt * 16 + col];
            cell<false, 0>(W0, sbias, hbuf[1], hbuf[1], hbuf[0], ho0, xw, xv, j4, ro0, ro1, wo);
            __syncthreads();
            cell<true, 1>(W1, sbias, hbuf[0], hbuf[3], hbuf[2], ho1, nullptr, nullptr, j4, ro0, ro1, wo);
        }
        {   // t = 10 (even body)
            float2 xv[2];
            #pragma unroll
            for (int mt = 0; mt < 2; ++mt) xv[mt] = xe[10 * 32 + mt * 16 + col];
            cell<false, 0>(W0, sbias, hbuf[0], hbuf[0], hbuf[1], ho0, xw, xv, j4, ro0, ro1, wo);
            __syncthreads();
            cell<true, 1>(W1, sbias, hbuf[1], hbuf[2], hbuf[3], ho1, nullptr, nullptr, j4, ro0, ro1, wo);
        }
    }
    // now: h0 cur = hbuf[1], h1 cur = hbuf[3]

    // ---------------- phase switch ----------------
    load_h_frags(W0, dWhh0, jA, quad);
    #pragma unroll
    for (int ks = 0; ks < 2; ++ks) {
        const int k0 = ks * 32 + quad * 8;
        W0.xR[ks] = cfrag(dWih0, fcW, jA,       k0, SRC);
        W0.xZ[ks] = cfrag(dWih0, fcW, jA + 64,  k0, SRC);
        W0.xN[ks] = cfrag(dWih0, fcW, jA + 128, k0, SNC);
    }
    load_h_frags(W1, dWhh1, jA, quad);
    load_x_frags(W1, dWih1, jA, quad);
    if (tid < 64) {   // decoder biases -> LDS (slots 2: dec-l0 +fc fold, 3: dec-l1)
        const int j = tid;
        const float f0 = fcb[0], f1 = fcb[1];
        sbias[512 +       j] = SRC * (dbih0[j] + dbhh0[j] + dWih0[j * 2] * f0 + dWih0[j * 2 + 1] * f1);
        sbias[512 +  64 + j] = SRC * (dbih0[64 + j] + dbhh0[64 + j] + dWih0[(64 + j) * 2] * f0 + dWih0[(64 + j) * 2 + 1] * f1);
        sbias[512 + 128 + j] = SNC * (dbih0[128 + j] + dWih0[(128 + j) * 2] * f0 + dWih0[(128 + j) * 2 + 1] * f1);
        sbias[512 + 192 + j] = SNC * dbhh0[128 + j];
        sbias[768 +       j] = SRC * (dbih1[j] + dbhh1[j]);
        sbias[768 +  64 + j] = SRC * (dbih1[64 + j] + dbhh1[64 + j]);
        sbias[768 + 128 + j] = SNC * dbih1[128 + j];
        sbias[768 + 192 + j] = SNC * dbhh1[128 + j];
    }
    f16x8 fcf[2];
    #pragma unroll
    for (int ks = 0; ks < 2; ++ks) {
        #pragma unroll
        for (int i = 0; i < 8; ++i) fcf[ks][i] = (f16)0.f;
        if (col < 2) fcf[ks] = wfrag(fcW, col, ks * 32 + quad * 8, 1.0f);
    }
    f32x4 pb;
    #pragma unroll
    for (int rg = 0; rg < 4; ++rg) pb[rg] = (quad == 0 && rg < 2) ? fcb[rg] : 0.f;
    __syncthreads();   // dec biases visible to all waves

    // FC: only 2 batch chunks of 16 -> waves 0,1 own them; 2,3 skip.
    const int cw = w & 1;
    float* __restrict__ op = out + (size_t)(r0 + cw * 16 + col) * (STEPS * 2);

    // ---------------- decoder step 0 (peeled, x-path) ----------------
    {
        f32x4 xw[6];
        #pragma unroll
        for (int rg = 0; rg < 4; ++rg) {
            xw[0][rg] = SRC * dWih0[(j4 + rg) * 2];        xw[1][rg] = SRC * dWih0[(j4 + rg) * 2 + 1];
            xw[2][rg] = SRC * dWih0[(64 + j4 + rg) * 2];   xw[3][rg] = SRC * dWih0[(64 + j4 + rg) * 2 + 1];
            xw[4][rg] = SNC * dWih0[(128 + j4 + rg) * 2];  xw[5][rg] = SNC * dWih0[(128 + j4 + rg) * 2 + 1];
        }
        float2 xv0[2];
        #pragma unroll
        for (int mt = 0; mt < 2; ++mt) xv0[mt] = xe[10 * 32 + mt * 16 + col];
        cell<false, 2>(W0, sbias, hbuf[1], hbuf[1], hbuf[0], ho0, xw, xv0, j4, ro0, ro1, wo);
        __syncthreads();
        cell<true, 3>(W1, sbias, hbuf[0], hbuf[3], hbuf[2], ho1, nullptr, nullptr, j4, ro0, ro1, wo);
        __syncthreads();
        if (w < 2) {
            f16x8 hb0 = *(const f16x8*)(hbuf[2] + ro0 + cw * 1024);
            f16x8 hb1 = *(const f16x8*)(hbuf[2] + ro1 + cw * 1024);
            f32x4 p = mfma16(fcf[0], hb0, pb);
            p = mfma16(fcf[1], hb1, p);
            if (quad == 0) *(float2*)op = make_float2(p[0], p[1]);
        }
        op += 2;
    }

    // ---------------- decoder: 39 pairs (odd, even) + 1 odd ----------
    #pragma unroll 1
    for (int sp = 0; sp < 39; ++sp) {
        cell<true, 2>(W0, sbias, hbuf[2], hbuf[0], hbuf[1], ho0, nullptr, nullptr, j4, ro0, ro1, wo);
        __syncthreads();
        cell<true, 3>(W1, sbias, hbuf[1], hbuf[2], hbuf[3], ho1, nullptr, nullptr, j4, ro0, ro1, wo);
        __syncthreads();
        if (w < 2) {
            f16x8 hb0 = *(const f16x8*)(hbuf[3] + ro0 + cw * 1024);
            f16x8 hb1 = *(const f16x8*)(hbuf[3] + ro1 + cw * 1024);
            f32x4 p = mfma16(fcf[0], hb0, pb);
            p = mfma16(fcf[1], hb1, p);
            if (quad == 0) *(float2*)op = make_float2(p[0], p[1]);
        }
        op += 2;
        cell<true, 2>(W0, sbias, hbuf[3], hbuf[1], hbuf[0], ho0, nullptr, nullptr, j4, ro0, ro1, wo);
        __syncthreads();
        cell<true, 3>(W1, sbias, hbuf[0], hbuf[3], hbuf[2], ho1, nullptr, nullptr, j4, ro0, ro1, wo);
        __syncthreads();
        if (w < 2) {
            f16x8 hb0 = *(const f16x8*)(hbuf[2] + ro0 + cw * 1024);
            f16x8 hb1 = *(const f16x8*)(hbuf[2] + ro1 + cw * 1024);
            f32x4 p = mfma16(fcf[0], hb0, pb);
            p = mfma16(fcf[1], hb1, p);
            if (quad == 0) *(float2*)op = make_float2(p[0], p[1]);
        }
        op += 2;
    }
    {   // s = 79 (odd body)
        cell<true, 2>(W0, sbias, hbuf[2], hbuf[0], hbuf[1], ho0, nullptr, nullptr, j4, ro0, ro1, wo);
        __syncthreads();
        cell<true, 3>(W1, sbias, hbuf[1], hbuf[2], hbuf[3], ho1, nullptr, nullptr, j4, ro0, ro1, wo);
        __syncthreads();
        if (w < 2) {
            f16x8 hb0 = *(const f16x8*)(hbuf[3] + ro0 + cw * 1024);
            f16x8 hb1 = *(const f16x8*)(hbuf[3] + ro1 + cw * 1024);
            f32x4 p = mfma16(fcf[0], hb0, pb);
            p = mfma16(fcf[1], hb1, p);
            if (quad == 0) *(float2*)op = make_float2(p[0], p[1]);
        }
    }
}

extern "C" void kernel_launch(void* const* d_in, const int* in_sizes, int n_in,
                              void* d_out, int out_size, void* d_ws, size_t ws_size,
                              hipStream_t stream) {
    (void)n_in; (void)out_size; (void)d_ws; (void)ws_size;

    const float* x     = (const float*)d_in[0];
    const float* eWih0 = (const float*)d_in[1];
    const float* eWhh0 = (const float*)d_in[2];
    const float* ebih0 = (const float*)d_in[3];
    const float* ebhh0 = (const float*)d_in[4];
    const float* eWih1 = (const float*)d_in[5];
    const float* eWhh1 = (const float*)d_in[6];
    const float* ebih1 = (const float*)d_in[7];
    const float* ebhh1 = (const float*)d_in[8];
    const float* dWih0 = (const float*)d_in[9];
    const float* dWhh0 = (const float*)d_in[10];
    const float* dbih0 = (const float*)d_in[11];
    const float* dbhh0 = (const float*)d_in[12];
    const float* dWih1 = (const float*)d_in[13];
    const float* dWhh1 = (const float*)d_in[14];
    const float* dbih1 = (const float*)d_in[15];
    const float* dbhh1 = (const float*)d_in[16];
    const float* fcW   = (const float*)d_in[17];
    const float* fcb   = (const float*)d_in[18];
    float* out = (float*)d_out;

    const int b = in_sizes[0] / (T_SEQ * 2);   // 32768
    dim3 grid(b / 32), block(256);
    hipLaunchKernelGGL(gru_traj_mfma11, grid, block, 0, stream,
        x, eWih0, eWhh0, ebih0, ebhh0, eWih1, eWhh1, ebih1, ebhh1,
        dWih0, dWhh0, dbih0, dbhh0, dWih1, dWhh1, dbih1, dbhh1,
        fcW, fcb, out);
}

// Round 7
// 463.597 us; speedup vs baseline: 1.1544x; 1.0049x over previous
//
#include <hip/hip_runtime.h>
#include <cstddef>

#define T_SEQ 11
#define STEPS 80

typedef _Float16 f16;
typedef _Float16 f16x4 __attribute__((ext_vector_type(4)));
typedef _Float16 f16x8 __attribute__((ext_vector_type(8)));
typedef float    f32x4 __attribute__((ext_vector_type(4)));

// Gate prescale folded into weights/biases: sigmoid args x -log2(e), tanh
// (n-path) args x +2*log2(e) -> epilogue uses raw exp2/rcp, no per-gate muls.
#define SRC (-1.44269504f)
#define SNC ( 2.88539008f)

__device__ __forceinline__ f32x4 mfma16(f16x8 a, f16x8 b, f32x4 c) {
    return __builtin_amdgcn_mfma_f32_16x16x32_f16(a, b, c, 0, 0, 0);
}
__device__ __forceinline__ float exp2r(float x) { return __builtin_amdgcn_exp2f(x); }

// A-frag: lane holds sc*W[row][k0..k0+7].
__device__ __forceinline__ f16x8 wfrag(const float* __restrict__ W, int row, int k0, float sc) {
    f16x8 r;
    #pragma unroll
    for (int i = 0; i < 8; ++i) r[i] = (f16)(sc * W[row * 64 + k0 + i]);
    return r;
}
// Composed decoder-l0 gi weights: sc*(Wih0[g][0]*fcW[0][k] + Wih0[g][1]*fcW[1][k])
__device__ __forceinline__ f16x8 cfrag(const float* __restrict__ Wih0,
                                       const float* __restrict__ fcW, int row, int k0, float sc) {
    f16x8 r;
    #pragma unroll
    for (int i = 0; i < 8; ++i)
        r[i] = (f16)(sc * (Wih0[row * 2] * fcW[k0 + i] + Wih0[row * 2 + 1] * fcW[64 + k0 + i]));
    return r;
}

// Weight fragments ONLY — biases (r5) and now fc frags/pb (r6->r7) live in
// LDS. Register ledger across rounds: occupancy = floor(512 / (VGPR +
// parked-AGPR)); r6 measured 84 VGPR -> 2.15 waves/SIMD => total ~178, just
// over the 512/3=170 line for 3 waves. Evicting fcf (8) + pb (4) targets
// total ~166 < 170 -> 3 waves/SIMD.
struct WSet {
    f16x8 xR[2], xZ[2], xN[2];   // gi-source weights (MFMA path)
    f16x8 hR[2], hZ[2], hN[2];   // recurrent weights
};

__device__ __forceinline__ void load_h_frags(WSet& W, const float* __restrict__ Whh,
                                             int jA, int quad)
{
    #pragma unroll
    for (int ks = 0; ks < 2; ++ks) {
        const int k0 = ks * 32 + quad * 8;
        W.hR[ks] = wfrag(Whh, jA,       k0, SRC);
        W.hZ[ks] = wfrag(Whh, jA + 64,  k0, SRC);
        W.hN[ks] = wfrag(Whh, jA + 128, k0, SNC);
    }
}
__device__ __forceinline__ void load_x_frags(WSet& W, const float* __restrict__ Wx,
                                             int jA, int quad)
{
    #pragma unroll
    for (int ks = 0; ks < 2; ++ks) {
        const int k0 = ks * 32 + quad * 8;
        W.xR[ks] = wfrag(Wx, jA,       k0, SRC);
        W.xZ[ks] = wfrag(Wx, jA + 64,  k0, SRC);
        W.xN[ks] = wfrag(Wx, jA + 128, k0, SNC);
    }
}

// One GRU cell, D[j][row]. 32 batch rows per block -> 2 mt chunks of 16.
// Biases read from LDS per cell (CT selects cell type slot), transient regs.
template<bool XM, int CT>
__device__ __forceinline__ void cell(const WSet& W, const float* __restrict__ sb,
    const f16* __restrict__ Xs, const f16* __restrict__ Hs, f16* __restrict__ Dst,
    f16x4 (&ho)[2],
    const f32x4* __restrict__ xw, const float2* __restrict__ xv,
    int j4, int ro0, int ro1, int wo)
{
    const f32x4 bR  = *(const f32x4*)(sb + CT * 256 +       j4);
    const f32x4 bZ  = *(const f32x4*)(sb + CT * 256 +  64 + j4);
    const f32x4 bNi = *(const f32x4*)(sb + CT * 256 + 128 + j4);
    const f32x4 bNh = *(const f32x4*)(sb + CT * 256 + 192 + j4);
    #pragma unroll
    for (int mt = 0; mt < 2; ++mt) {
        const int mo = mt * 1024;
        f16x8 hb0 = *(const f16x8*)(Hs + ro0 + mo);
        f16x8 hb1 = *(const f16x8*)(Hs + ro1 + mo);
        f32x4 aR  = mfma16(W.hR[0], hb0, bR);
        f32x4 aZ  = mfma16(W.hZ[0], hb0, bZ);
        f32x4 aNh = mfma16(W.hN[0], hb0, bNh);
        aR  = mfma16(W.hR[1], hb1, aR);
        aZ  = mfma16(W.hZ[1], hb1, aZ);
        aNh = mfma16(W.hN[1], hb1, aNh);
        f32x4 aNi;
        if constexpr (XM) {
            f16x8 xb0 = *(const f16x8*)(Xs + ro0 + mo);
            f16x8 xb1 = *(const f16x8*)(Xs + ro1 + mo);
            aR  = mfma16(W.xR[0], xb0, aR);    aR  = mfma16(W.xR[1], xb1, aR);
            aZ  = mfma16(W.xZ[0], xb0, aZ);    aZ  = mfma16(W.xZ[1], xb1, aZ);
            aNi = mfma16(W.xN[0], xb0, bNi);   aNi = mfma16(W.xN[1], xb1, aNi);
        } else {
            const float x0 = xv[mt].x, x1 = xv[mt].y;
            aR  += x0 * xw[0] + x1 * xw[1];
            aZ  += x0 * xw[2] + x1 * xw[3];
            aNi  = bNi + x0 * xw[4] + x1 * xw[5];
        }
        f16x4 o;
        #pragma unroll
        for (int i = 0; i < 4; ++i) {
            const float r = __builtin_amdgcn_rcpf(1.f + exp2r(aR[i]));
            const float z = __builtin_amdgcn_rcpf(1.f + exp2r(aZ[i]));
            const float n = 1.f - 2.f * __builtin_amdgcn_rcpf(1.f + exp2r(aNi[i] + r * aNh[i]));
            const float h = n + z * ((float)ho[mt][i] - n);
            o[i] = (f16)h;
        }
        ho[mt] = o;
        *(f16x4*)(Dst + wo + mo) = o;
    }
}

__global__ __launch_bounds__(256, 3)
void gru_traj_mfma12(
    const float* __restrict__ x,
    const float* __restrict__ eWih0, const float* __restrict__ eWhh0,
    const float* __restrict__ ebih0, const float* __restrict__ ebhh0,
    const float* __restrict__ eWih1, const float* __restrict__ eWhh1,
    const float* __restrict__ ebih1, const float* __restrict__ ebhh1,
    const float* __restrict__ dWih0, const float* __restrict__ dWhh0,
    const float* __restrict__ dbih0, const float* __restrict__ dbhh0,
    const float* __restrict__ dWih1, const float* __restrict__ dWhh1,
    const float* __restrict__ dbih1, const float* __restrict__ dbhh1,
    const float* __restrict__ fcW,  const float* __restrict__ fcb,
    float* __restrict__ out)
{
    // buffers: [0,1]=h0 double-buffer, [2,3]=h1 double-buffer, XOR-swizzled.
    __shared__ f16 hbuf[4][32 * 64];     // 16 KB
    __shared__ float2 xe[T_SEQ * 32];    // [t][row], 2.75 KB
    __shared__ float sbias[4 * 256];     // 4 cell types x {bR,bZ,bNi,bNh}[64], 4 KB
    __shared__ f16 sfc[1024];            // fc A-frags (2 x 512), 2 KB
    __shared__ float sfcb[2];            // fc bias

    const int tid  = threadIdx.x;
    const int lane = tid & 63;
    const int w    = __builtin_amdgcn_readfirstlane(tid >> 6);
    const int quad = lane >> 4;
    const int col  = lane & 15;
    const int r0   = blockIdx.x * 32;

    // coalesced x staging: consecutive tid -> consecutive global float2
    {
        const float2* x2 = (const float2*)x;
        for (int i = tid; i < 32 * T_SEQ; i += 256) {
            const int row = i / T_SEQ, t = i - row * T_SEQ;
            xe[t * 32 + row] = x2[(size_t)r0 * T_SEQ + i];
        }
    }
    for (int i = tid; i < 32 * 64; i += 256) { hbuf[0][i] = (f16)0.f; hbuf[2][i] = (f16)0.f; }
    if (tid < 64) {   // encoder biases -> LDS (slots 0: enc-l0, 1: enc-l1)
        const int j = tid;
        sbias[       j] = SRC * (ebih0[j] + ebhh0[j]);
        sbias[ 64 + j] = SRC * (ebih0[64 + j] + ebhh0[64 + j]);
        sbias[128 + j] = SNC * ebih0[128 + j];
        sbias[192 + j] = SNC * ebhh0[128 + j];
        sbias[256 +       j] = SRC * (ebih1[j] + ebhh1[j]);
        sbias[256 +  64 + j] = SRC * (ebih1[64 + j] + ebhh1[64 + j]);
        sbias[256 + 128 + j] = SNC * ebih1[128 + j];
        sbias[256 + 192 + j] = SNC * ebhh1[128 + j];
    }
    // fc frag staging (layout verified in r4): lane l of frag ks holds
    // fcW[col][k-slice] for col<2 else 0, as f16x8 at sfc[ks*512 + l*8].
    for (int e = tid; e < 1024; e += 256) {
        const int ks = e >> 9, rr = e & 511;
        const int lne = rr >> 3, ki = rr & 7;
        const int c = lne & 15, q = lne >> 4;
        const int k = ks * 32 + q * 8 + ki;
        sfc[ks * 512 + lne * 8 + ki] = (c < 2) ? (f16)fcW[c * 64 + k] : (f16)0.f;
    }
    if (tid < 2) sfcb[tid] = fcb[tid];

    // Swizzle (halves): phys(row,k) = row*64 + (((k>>3)^(row&7))<<3) + (k&7)
    const int c7  = col & 7;
    const int ro0 = col * 64 + ((quad ^ c7) << 3);
    const int ro1 = col * 64 + (((4 + quad) ^ c7) << 3);
    const int wo  = col * 64 + ((((w << 1) | (quad >> 1)) ^ c7) << 3) + ((quad & 1) << 2);

    const int jA = w * 16 + col;
    const int j4 = w * 16 + quad * 4;

    f16x4 ho0[2], ho1[2];
    #pragma unroll
    for (int mt = 0; mt < 2; ++mt) {
        #pragma unroll
        for (int i = 0; i < 4; ++i) { ho0[mt][i] = (f16)0.f; ho1[mt][i] = (f16)0.f; }
    }

    WSet W0, W1;
    load_h_frags(W0, eWhh0, jA, quad);
    load_h_frags(W1, eWhh1, jA, quad);
    load_x_frags(W1, eWih1, jA, quad);
    {
        f32x4 xw[6];
        #pragma unroll
        for (int rg = 0; rg < 4; ++rg) {
            xw[0][rg] = SRC * eWih0[(j4 + rg) * 2];        xw[1][rg] = SRC * eWih0[(j4 + rg) * 2 + 1];
            xw[2][rg] = SRC * eWih0[(64 + j4 + rg) * 2];   xw[3][rg] = SRC * eWih0[(64 + j4 + rg) * 2 + 1];
            xw[4][rg] = SNC * eWih0[(128 + j4 + rg) * 2];  xw[5][rg] = SNC * eWih0[(128 + j4 + rg) * 2 + 1];
        }
        __syncthreads();

        // ---------------- encoder: static buffers, 1 barrier/step ----------------
        #pragma unroll 1
        for (int t = 0; t < T_SEQ - 1; t += 2) {
            float2 xv[2];
            #pragma unroll
            for (int mt = 0; mt < 2; ++mt) xv[mt] = xe[t * 32 + mt * 16 + col];
            cell<false, 0>(W0, sbias, hbuf[0], hbuf[0], hbuf[1], ho0, xw, xv, j4, ro0, ro1, wo);
            __syncthreads();
            cell<true, 1>(W1, sbias, hbuf[1], hbuf[2], hbuf[3], ho1, nullptr, nullptr, j4, ro0, ro1, wo);
            #pragma unroll
            for (int mt = 0; mt < 2; ++mt) xv[mt] = xe[(t + 1) * 32 + mt * 16 + col];
            cell<false, 0>(W0, sbias, hbuf[1], hbuf[1], hbuf[0], ho0, xw, xv, j4, ro0, ro1, wo);
            __syncthreads();
            cell<true, 1>(W1, sbias, hbuf[0], hbuf[3], hbuf[2], ho1, nullptr, nullptr, j4, ro0, ro1, wo);
        }
        {   // t = 10 (even body)
            float2 xv[2];
            #pragma unroll
            for (int mt = 0; mt < 2; ++mt) xv[mt] = xe[10 * 32 + mt * 16 + col];
            cell<false, 0>(W0, sbias, hbuf[0], hbuf[0], hbuf[1], ho0, xw, xv, j4, ro0, ro1, wo);
            __syncthreads();
            cell<true, 1>(W1, sbias, hbuf[1], hbuf[2], hbuf[3], ho1, nullptr, nullptr, j4, ro0, ro1, wo);
        }
    }
    // now: h0 cur = hbuf[1], h1 cur = hbuf[3]

    // ---------------- phase switch ----------------
    load_h_frags(W0, dWhh0, jA, quad);
    #pragma unroll
    for (int ks = 0; ks < 2; ++ks) {
        const int k0 = ks * 32 + quad * 8;
        W0.xR[ks] = cfrag(dWih0, fcW, jA,       k0, SRC);
        W0.xZ[ks] = cfrag(dWih0, fcW, jA + 64,  k0, SRC);
        W0.xN[ks] = cfrag(dWih0, fcW, jA + 128, k0, SNC);
    }
    load_h_frags(W1, dWhh1, jA, quad);
    load_x_frags(W1, dWih1, jA, quad);
    if (tid < 64) {   // decoder biases -> LDS (slots 2: dec-l0 +fc fold, 3: dec-l1)
        const int j = tid;
        const float f0 = fcb[0], f1 = fcb[1];
        sbias[512 +       j] = SRC * (dbih0[j] + dbhh0[j] + dWih0[j * 2] * f0 + dWih0[j * 2 + 1] * f1);
        sbias[512 +  64 + j] = SRC * (dbih0[64 + j] + dbhh0[64 + j] + dWih0[(64 + j) * 2] * f0 + dWih0[(64 + j) * 2 + 1] * f1);
        sbias[512 + 128 + j] = SNC * (dbih0[128 + j] + dWih0[(128 + j) * 2] * f0 + dWih0[(128 + j) * 2 + 1] * f1);
        sbias[512 + 192 + j] = SNC * dbhh0[128 + j];
        sbias[768 +       j] = SRC * (dbih1[j] + dbhh1[j]);
        sbias[768 +  64 + j] = SRC * (dbih1[64 + j] + dbhh1[64 + j]);
        sbias[768 + 128 + j] = SNC * dbih1[128 + j];
        sbias[768 + 192 + j] = SNC * dbhh1[128 + j];
    }
    __syncthreads();   // dec biases visible to all waves

    // FC: only 2 batch chunks of 16 -> waves 0,1 own them; 2,3 skip.
    // fc frags + bias read from LDS per step (r7: evicted from registers).
    const int cw = w & 1;
    float* __restrict__ op = out + (size_t)(r0 + cw * 16 + col) * (STEPS * 2);

    auto FCout = [&](const f16* h1c) {
        if (w < 2) {
            f32x4 pb;
            const float f0 = sfcb[0], f1 = sfcb[1];
            pb[0] = (quad == 0) ? f0 : 0.f;
            pb[1] = (quad == 0) ? f1 : 0.f;
            pb[2] = 0.f; pb[3] = 0.f;
            f16x8 fc0 = *(const f16x8*)(sfc + lane * 8);
            f16x8 fc1 = *(const f16x8*)(sfc + 512 + lane * 8);
            f16x8 hb0 = *(const f16x8*)(h1c + ro0 + cw * 1024);
            f16x8 hb1 = *(const f16x8*)(h1c + ro1 + cw * 1024);
            f32x4 p = mfma16(fc0, hb0, pb);
            p = mfma16(fc1, hb1, p);
            if (quad == 0) *(float2*)op = make_float2(p[0], p[1]);
        }
        op += 2;
    };

    // ---------------- decoder step 0 (peeled, x-path) ----------------
    {
        f32x4 xw[6];
        #pragma unroll
        for (int rg = 0; rg < 4; ++rg) {
            xw[0][rg] = SRC * dWih0[(j4 + rg) * 2];        xw[1][rg] = SRC * dWih0[(j4 + rg) * 2 + 1];
            xw[2][rg] = SRC * dWih0[(64 + j4 + rg) * 2];   xw[3][rg] = SRC * dWih0[(64 + j4 + rg) * 2 + 1];
            xw[4][rg] = SNC * dWih0[(128 + j4 + rg) * 2];  xw[5][rg] = SNC * dWih0[(128 + j4 + rg) * 2 + 1];
        }
        float2 xv0[2];
        #pragma unroll
        for (int mt = 0; mt < 2; ++mt) xv0[mt] = xe[10 * 32 + mt * 16 + col];
        cell<false, 2>(W0, sbias, hbuf[1], hbuf[1], hbuf[0], ho0, xw, xv0, j4, ro0, ro1, wo);
        __syncthreads();
        cell<true, 3>(W1, sbias, hbuf[0], hbuf[3], hbuf[2], ho1, nullptr, nullptr, j4, ro0, ro1, wo);
        __syncthreads();
        FCout(hbuf[2]);
    }

    // ---------------- decoder: 39 pairs (odd, even) + 1 odd ----------
    #pragma unroll 1
    for (int sp = 0; sp < 39; ++sp) {
        cell<true, 2>(W0, sbias, hbuf[2], hbuf[0], hbuf[1], ho0, nullptr, nullptr, j4, ro0, ro1, wo);
        __syncthreads();
        cell<true, 3>(W1, sbias, hbuf[1], hbuf[2], hbuf[3], ho1, nullptr, nullptr, j4, ro0, ro1, wo);
        __syncthreads();
        FCout(hbuf[3]);
        cell<true, 2>(W0, sbias, hbuf[3], hbuf[1], hbuf[0], ho0, nullptr, nullptr, j4, ro0, ro1, wo);
        __syncthreads();
        cell<true, 3>(W1, sbias, hbuf[0], hbuf[3], hbuf[2], ho1, nullptr, nullptr, j4, ro0, ro1, wo);
        __syncthreads();
        FCout(hbuf[2]);
    }
    {   // s = 79 (odd body)
        cell<true, 2>(W0, sbias, hbuf[2], hbuf[0], hbuf[1], ho0, nullptr, nullptr, j4, ro0, ro1, wo);
        __syncthreads();
        cell<true, 3>(W1, sbias, hbuf[1], hbuf[2], hbuf[3], ho1, nullptr, nullptr, j4, ro0, ro1, wo);
        __syncthreads();
        FCout(hbuf[3]);
    }
}

extern "C" void kernel_launch(void* const* d_in, const int* in_sizes, int n_in,
                              void* d_out, int out_size, void* d_ws, size_t ws_size,
                              hipStream_t stream) {
    (void)n_in; (void)out_size; (void)d_ws; (void)ws_size;

    const float* x     = (const float*)d_in[0];
    const float* eWih0 = (const float*)d_in[1];
    const float* eWhh0 = (const float*)d_in[2];
    const float* ebih0 = (const float*)d_in[3];
    const float* ebhh0 = (const float*)d_in[4];
    const float* eWih1 = (const float*)d_in[5];
    const float* eWhh1 = (const float*)d_in[6];
    const float* ebih1 = (const float*)d_in[7];
    const float* ebhh1 = (const float*)d_in[8];
    const float* dWih0 = (const float*)d_in[9];
    const float* dWhh0 = (const float*)d_in[10];
    const float* dbih0 = (const float*)d_in[11];
    const float* dbhh0 = (const float*)d_in[12];
    const float* dWih1 = (const float*)d_in[13];
    const float* dWhh1 = (const float*)d_in[14];
    const float* dbih1 = (const float*)d_in[15];
    const float* dbhh1 = (const float*)d_in[16];
    const float* fcW   = (const float*)d_in[17];
    const float* fcb   = (const float*)d_in[18];
    float* out = (float*)d_out;

    const int b = in_sizes[0] / (T_SEQ * 2);   // 32768
    dim3 grid(b / 32), block(256);
    hipLaunchKernelGGL(gru_traj_mfma12, grid, block, 0, stream,
        x, eWih0, eWhh0, ebih0, ebhh0, eWih1, eWhh1, ebih1, ebhh1,
        dWih0, dWhh0, dbih0, dbhh0, dWih1, dWhh1, dbih1, dbhh1,
        fcW, fcb, out);
}